// Round 15
// baseline (137.803 us; speedup 1.0000x reference)
//
#include <hip/hip_runtime.h>
#include <hip/hip_fp16.h>

// QLinear with per-k fp16 requantized accumulation (mptorch fma semantics).
// out = q16( q16_scan_fma( q8(x) @ q8(W)^T ) + q8(b) )
//
// Round-15: ONE-WAVE BLOCKS to break the convoy. R12-14 showed time ~=
// LDS + VALU serial (both pipes ~55-60% busy, complementary); in-wave
// pipelining is defeated by IR-level load sinking (VGPR pinned at 40 in
// R13 AND R14). The barrier is what phase-aligns all 8 waves/CU; but the
// staged LDS data is wave-private (global_load_lds = wave base + lane*16),
// so with 64-thread blocks no inter-wave sync is needed at all: per-wave
// asm s_waitcnt drain replaces __syncthreads, 8 free-running waves/CU
// decorrelate, LDS bursts of one wave overlap VALU of the others.
// Per-lane economy identical to R12: wave tile 32m x 32n, lane 4m x 4n,
// per k-quad 3 ds_read_b128 + 8 quarter-rate cvt + 32 pk_fma.
// Numerics: quad body + strict ascending-k order byte-identical to R12-14.

#define M_DIM 2048
#define N_DIM 1024
#define K_DIM 1024

#define BT 32                  // block tile: 32m x 32n, one wave
#define BK 64
#define NCHUNK (K_DIM / BK)    // 16

typedef unsigned u32;
typedef float f32x2 __attribute__((ext_vector_type(2)));
typedef _Float16 f16x2 __attribute__((ext_vector_type(2)));

// exact E4M3 (exp=4, man=3) quantization of an fp32 value, result fp32
__device__ __forceinline__ float quant_e4m3(float v) {
  unsigned au = __float_as_uint(v) & 0x7fffffffu;
  if (au == 0u) return v;                 // +-0
  int e = (int)(au >> 23) - 127;          // floor(log2|v|) for normals
  if (e < -6) e = -6;                     // fp32 subnorms hit the clamp too
  float s  = __uint_as_float((unsigned)(130 - e) << 23);  // 2^(3-e), exact
  float is = __uint_as_float((unsigned)(124 + e) << 23);  // 2^(e-3), exact
  float r = rintf(v * s) * is;            // RNE (half-to-even), all steps exact
  return fminf(240.f, fmaxf(-240.f, r));
}

// exact encode of an E4M3-representable fp32 value to an OCP e4m3fn byte.
__device__ __forceinline__ u32 enc_e4m3(float v) {
  unsigned au = __float_as_uint(v);
  unsigned sg = (au >> 24) & 0x80u;
  unsigned a = au & 0x7fffffffu;
  if (a == 0u) return sg;                 // +-0
  int e = (int)(a >> 23) - 127;           // value is f32-normal (>= 2^-9)
  unsigned man = (a >> 20) & 7u;
  if (e >= -6) return sg | ((unsigned)(e + 7) << 3) | man;   // normal
  return sg | ((8u | man) >> (-6 - e));   // subnormal: multiples of 2^-9
}

// ---------- fused prep (identical to round-12/13/14, proven) ----------
// blocks [0,2048): x [M][K] -> xP[K/2][M] u32 = {q(x[m][2t]), q(x[m][2t+1])} f16
// blocks [2048,3072): w [N][K] -> wB u32[K/4][N] (uint4-grouped e4m3 bytes)
__global__ __launch_bounds__(256) void prep_kernel(const float* __restrict__ x,
                                                   const float* __restrict__ w,
                                                   u32* __restrict__ xP,
                                                   u32* __restrict__ wB) {
  __shared__ float tile[32][33];
  const int tx = threadIdx.x & 31;
  const int ty = threadIdx.x >> 5;
  if (blockIdx.x < 2048) {
    const int c0 = (blockIdx.x & 31) * 32;   // k offset
    const int r0 = (blockIdx.x >> 5) * 32;   // m offset
#pragma unroll
    for (int i = 0; i < 4; i++) {
      int r = r0 + ty + i * 8;
      tile[ty + i * 8][tx] = quant_e4m3(x[(size_t)r * K_DIM + c0 + tx]);  // [m_l][k_l]
    }
    __syncthreads();
#pragma unroll
    for (int i = 0; i < 2; i++) {
      int tl = ty + i * 8;                   // k-pair local 0..15
      u32 lo = (u32)__half_as_ushort(__float2half(tile[tx][2 * tl]));
      u32 hi = (u32)__half_as_ushort(__float2half(tile[tx][2 * tl + 1]));
      xP[(size_t)(c0 / 2 + tl) * M_DIM + r0 + tx] = lo | (hi << 16);
    }
  } else {
    const int b = blockIdx.x - 2048;
    const int k0t = (b & 31) * 32;
    const int n0t = (b >> 5) * 32;
#pragma unroll
    for (int i = 0; i < 4; i++) {
      int n = n0t + ty + i * 8;
      tile[ty + i * 8][tx] = quant_e4m3(w[(size_t)n * K_DIM + k0t + tx]);  // [n_l][k_l]
    }
    __syncthreads();
    const int u = threadIdx.x & 3;          // u32 slot in uint4
    const int cl = (threadIdx.x >> 2) & 7;  // n-chunk local (4 n)
    const int ql = (threadIdx.x >> 5) & 7;  // k-quad local
    const int nl = 4 * cl + 2 * (u & 1);    // n base for this u32
    const int kl = 4 * ql + 2 * (u >> 1);   // k base for this u32
    u32 v = enc_e4m3(tile[nl][kl])
          | (enc_e4m3(tile[nl + 1][kl]) << 8)
          | (enc_e4m3(tile[nl][kl + 1]) << 16)
          | (enc_e4m3(tile[nl + 1][kl + 1]) << 24);
    wB[(size_t)(k0t / 4 + ql) * N_DIM + n0t + (cl << 2) + u] = v;
  }
}

// ---------- GEMM ----------

__device__ __forceinline__ void gld16(const void* g, void* l) {
  __builtin_amdgcn_global_load_lds((const __attribute__((address_space(1))) u32*)g,
                                   (__attribute__((address_space(3))) u32*)l, 16, 0, 0);
}

// decode one fp8 byte-pair (word HI of v) to packed fp16 pair {b0, b1}.
#if __has_builtin(__builtin_amdgcn_cvt_scalef32_pk_f16_fp8)
template <int HI>
__device__ __forceinline__ u32 fp8x2_h2(u32 v) {
  f16x2 h = __builtin_amdgcn_cvt_scalef32_pk_f16_fp8((int)v, 1.0f, HI != 0);
  return __builtin_bit_cast(u32, h);      // 1 instr per 2 values (quarter-rate)
}
#else
template <int HI>
__device__ __forceinline__ u32 fp8x2_h2(u32 v) {
  f32x2 f = __builtin_amdgcn_cvt_pk_f32_fp8((int)v, HI);
  u32 r;
  asm("v_cvt_pkrtz_f16_f32 %0, %1, %2" : "=v"(r) : "v"(f[0]), "v"(f[1]));
  return r;
}
#endif

// acc = pk_fma(splat(x.lo), w, acc)  -- first k of the packed x pair
__device__ __forceinline__ void pkfma_lo(u32& acc, u32 x, u32 w) {
  asm("v_pk_fma_f16 %0, %1, %2, %0 op_sel:[0,0,0] op_sel_hi:[0,1,1]"
      : "+v"(acc) : "v"(x), "v"(w));
}
// acc = pk_fma(splat(x.hi), w, acc)  -- second k of the packed x pair
__device__ __forceinline__ void pkfma_hi(u32& acc, u32 x, u32 w) {
  asm("v_pk_fma_f16 %0, %1, %2, %0 op_sel:[1,0,0] op_sel_hi:[1,1,1]"
      : "+v"(acc) : "v"(x), "v"(w));
}

// xP [K/2][M] u32 (f16 k-pair packed), wB u32[K/4][N] (e4m3 bytes), b [N],
// out [M][N] fp32.  64 threads = ONE wave; tile 32m x 32n; lane 4m x 4n
// (tm = lane>>3, tn = lane&7).  No __syncthreads -- wave-private LDS,
// per-wave asm waitcnt drains. 2048 blocks -> 8 free-running waves/CU.
__global__ __launch_bounds__(64, 2) void gemm_qfma(const u32* __restrict__ xP,
                                                   const u32* __restrict__ wB,
                                                   const float* __restrict__ b,
                                                   float* __restrict__ outp) {
  __shared__ __align__(16) u32 xs[2][BK / 2][BT];    // 2 x 32 x 32 u32 = 8 KB
  __shared__ __align__(16) u32 wsu[2][BK / 4][BT];   // 2 x 16 x 32 u32 = 4 KB
  const int l = threadIdx.x;        // 0..63
  const int tn = l & 7;             // n-group: cols 4tn..4tn+3
  const int tm = l >> 3;            // m-group: rows 4tm..4tm+3
  const int bn0 = blockIdx.x * BT;
  const int bm0 = blockIdx.y * BT;

  u32 acc[4][2];
#pragma unroll
  for (int i = 0; i < 4; i++) { acc[i][0] = 0u; acc[i][1] = 0u; }

  // staging: linear LDS (wave base + lane*16). lane l, pass p covers
  // u32 idx p*256 + l*4 -> row p*8 + (l>>3), col (l&7)*4 (both operands).
  const u32* xsrc = xP + (size_t)(l >> 3) * M_DIM + bm0 + ((l & 7) << 2);
  const u32* wsrc = wB + (size_t)(l >> 3) * N_DIM + bn0 + ((l & 7) << 2);

  auto stage = [&](int ch, int buf) {
    const u32* xp = xsrc + (size_t)ch * (BK / 2) * M_DIM;
    char* xl = (char*)&xs[buf][0][0] + l * 16;
#pragma unroll
    for (int p = 0; p < 4; p++)                      // 32 x 32 u32 = 4 KB
      gld16(xp + (size_t)(p * 8) * M_DIM, xl + p * 1024);
    const u32* wp = wsrc + (size_t)ch * (BK / 4) * N_DIM;
    char* wl = (char*)&wsu[buf][0][0] + l * 16;
#pragma unroll
    for (int p = 0; p < 2; p++)                      // 16 x 32 u32 = 2 KB
      gld16(wp + (size_t)(p * 8) * N_DIM, wl + p * 1024);
  };

  // one k-quad: decode w (8 quarter-rate cvt) + 32 pk_fma.
  // strict k order per accumulator: k0 (lo), k1 (hi), k2 (lo), k3 (hi).
  auto quad = [&](const uint4& xv, const uint4& xv2, const uint4& wq) {
    const u32 wk0a = fp8x2_h2<0>(wq.x);   // k0: n01
    const u32 wk1a = fp8x2_h2<1>(wq.x);   // k1: n01
    const u32 wk0b = fp8x2_h2<0>(wq.y);   // k0: n23
    const u32 wk1b = fp8x2_h2<1>(wq.y);   // k1: n23
    const u32 wk2a = fp8x2_h2<0>(wq.z);   // k2: n01
    const u32 wk3a = fp8x2_h2<1>(wq.z);   // k3: n01
    const u32 wk2b = fp8x2_h2<0>(wq.w);   // k2: n23
    const u32 wk3b = fp8x2_h2<1>(wq.w);   // k3: n23
    pkfma_lo(acc[0][0], xv.x, wk0a); pkfma_lo(acc[0][1], xv.x, wk0b);
    pkfma_lo(acc[1][0], xv.y, wk0a); pkfma_lo(acc[1][1], xv.y, wk0b);
    pkfma_lo(acc[2][0], xv.z, wk0a); pkfma_lo(acc[2][1], xv.z, wk0b);
    pkfma_lo(acc[3][0], xv.w, wk0a); pkfma_lo(acc[3][1], xv.w, wk0b);
    pkfma_hi(acc[0][0], xv.x, wk1a); pkfma_hi(acc[0][1], xv.x, wk1b);
    pkfma_hi(acc[1][0], xv.y, wk1a); pkfma_hi(acc[1][1], xv.y, wk1b);
    pkfma_hi(acc[2][0], xv.z, wk1a); pkfma_hi(acc[2][1], xv.z, wk1b);
    pkfma_hi(acc[3][0], xv.w, wk1a); pkfma_hi(acc[3][1], xv.w, wk1b);
    pkfma_lo(acc[0][0], xv2.x, wk2a); pkfma_lo(acc[0][1], xv2.x, wk2b);
    pkfma_lo(acc[1][0], xv2.y, wk2a); pkfma_lo(acc[1][1], xv2.y, wk2b);
    pkfma_lo(acc[2][0], xv2.z, wk2a); pkfma_lo(acc[2][1], xv2.z, wk2b);
    pkfma_lo(acc[3][0], xv2.w, wk2a); pkfma_lo(acc[3][1], xv2.w, wk2b);
    pkfma_hi(acc[0][0], xv2.x, wk3a); pkfma_hi(acc[0][1], xv2.x, wk3b);
    pkfma_hi(acc[1][0], xv2.y, wk3a); pkfma_hi(acc[1][1], xv2.y, wk3b);
    pkfma_hi(acc[2][0], xv2.z, wk3a); pkfma_hi(acc[2][1], xv2.z, wk3b);
    pkfma_hi(acc[3][0], xv2.w, wk3a); pkfma_hi(acc[3][1], xv2.w, wk3b);
  };

  auto compute = [&](int buf) {
#pragma unroll
    for (int q = 0; q < BK / 4; q++) {      // k-quad: k = 4q .. 4q+3
      const uint4 xv  = *reinterpret_cast<const uint4*>(&xs[buf][2 * q][tm << 2]);
      const uint4 xv2 = *reinterpret_cast<const uint4*>(&xs[buf][2 * q + 1][tm << 2]);
      const uint4 wq  = *reinterpret_cast<const uint4*>(&wsu[buf][q][tn << 2]);
      quad(xv, xv2, wq);
    }
  };

  // per-wave drain: replaces __syncthreads (block = 1 wave, LDS is private).
  // "memory" clobber orders the surrounding ds_reads/DMA; sched_barrier per
  // rule #18 blocks hoisting past the wait.
  auto drain = [&]() {
    asm volatile("s_waitcnt vmcnt(0) lgkmcnt(0)" ::: "memory");
    __builtin_amdgcn_sched_barrier(0);
  };

  stage(0, 0);
  drain();
#pragma unroll 1
  for (int ch = 0; ch < NCHUNK; ch++) {
    if (ch + 1 < NCHUNK) stage(ch + 1, (ch + 1) & 1);  // issue-before-compute
    compute(ch & 1);
    drain();                     // next chunk's staged data is now visible
  }

  // epilogue: out = fp16RNE(acc + q8(b)), stored fp32 (fp32 add exact here)
  const int nc = bn0 + (tn << 2);
  float4 bq;
  bq.x = quant_e4m3(b[nc + 0]);
  bq.y = quant_e4m3(b[nc + 1]);
  bq.z = quant_e4m3(b[nc + 2]);
  bq.w = quant_e4m3(b[nc + 3]);
#pragma unroll
  for (int i = 0; i < 4; i++) {
    __half2 a0 = *reinterpret_cast<__half2*>(&acc[i][0]);  // n0,n1
    __half2 a1 = *reinterpret_cast<__half2*>(&acc[i][1]);  // n2,n3
    float4 o;
    o.x = __half2float(__float2half(__low2float(a0)  + bq.x));
    o.y = __half2float(__float2half(__high2float(a0) + bq.y));
    o.z = __half2float(__float2half(__low2float(a1)  + bq.z));
    o.w = __half2float(__float2half(__high2float(a1) + bq.w));
    *reinterpret_cast<float4*>(
        outp + (size_t)(bm0 + (tm << 2) + i) * N_DIM + nc) = o;
  }
}

extern "C" void kernel_launch(void* const* d_in, const int* in_sizes, int n_in,
                              void* d_out, int out_size, void* d_ws, size_t ws_size,
                              hipStream_t stream) {
  const float* x = (const float*)d_in[0];   // [2048][1024]
  const float* w = (const float*)d_in[1];   // [1024][1024] (out_f, in_f)
  const float* b = (const float*)d_in[2];   // [1024]
  float* outp = (float*)d_out;              // [2048][1024] fp32

  char* ws_ = (char*)d_ws;
  u32* xP = (u32*)ws_;                        // [K/2][M] u32 f16-pairs, 4 MiB
  u32* wB = (u32*)(ws_ + (size_t)(4 << 20));  // [K/4][N] u32 bytes,     1 MiB

  hipLaunchKernelGGL(prep_kernel, dim3(2048 + 1024), dim3(256), 0, stream,
                     x, w, xP, wB);
  hipLaunchKernelGGL(gemm_qfma, dim3(N_DIM / BT, M_DIM / BT), dim3(64), 0, stream,
                     xP, wB, b, outp);
}